// Round 9
// baseline (68.686 us; speedup 1.0000x reference)
//
#include <hip/hip_runtime.h>
#include <cstdint>
#include <cstddef>

// Dims (fixed by the reference)
#define R_   16
#define NH_  8
#define D_   32
#define C_   256
#define B_   16
#define XY_  1024      // 32*32
#define RH_  128       // R_*NH_
#define KD_  4096      // R_*NH_*D_
#define NPOS (B_*XY_)  // 16384 positions

#define LD4(p) (*reinterpret_cast<const float4*>(p))

// ---------------------------------------------------------------------------
// Precompute, 2x parallel (256 blocks): bid = rh*2 + half.
//   half 0: k[d] = Wk[r,h*D+d,:]·rims[r,:]+bk  ->  WLt[c][rh], c0[rh]
//   half 1: v[d] = Wv[...]·rims+bv             ->  Uo[rh][c]
// ---------------------------------------------------------------------------
__global__ __launch_bounds__(256)
void rims_precompute(const float* __restrict__ rims,
                     const float* __restrict__ Wk,
                     const float* __restrict__ bk,
                     const float* __restrict__ Wv,
                     const float* __restrict__ bv,
                     const float* __restrict__ Wq,
                     const float* __restrict__ bq,
                     const float* __restrict__ Wm,
                     float* __restrict__ WLt,
                     float* __restrict__ Uo,
                     float* __restrict__ c0o)
{
    const int bid  = blockIdx.x;       // 0..255
    const int rh   = bid >> 1;         // 0..127
    const int half = bid & 1;          // 0: k/WLt, 1: v/Uo
    const int r    = rh >> 3;
    const int h    = rh & 7;
    const int tid  = threadIdx.x;

    __shared__ float kv[D_];

    {
        const int d    = tid >> 3;     // 0..31
        const int part = tid & 7;      // 0..7
        const float* Wsrc = (half ? Wv : Wk)
                          + ((size_t)r * 256 + h * D_ + d) * C_ + part * 32;
        const float* rr   = rims + r * C_ + part * 32;
        float a0 = 0.f, a1 = 0.f, a2 = 0.f, a3 = 0.f;
        #pragma unroll
        for (int j = 0; j < 8; ++j) {
            const float4 wv4 = LD4(Wsrc + j * 4);
            const float4 xv4 = LD4(rr + j * 4);
            a0 = fmaf(wv4.x, xv4.x, a0); a1 = fmaf(wv4.y, xv4.y, a1);
            a2 = fmaf(wv4.z, xv4.z, a2); a3 = fmaf(wv4.w, xv4.w, a3);
        }
        float acc = (a0 + a1) + (a2 + a3);
        acc += __shfl_xor(acc, 1);
        acc += __shfl_xor(acc, 2);
        acc += __shfl_xor(acc, 4);
        if (part == 0)
            kv[d] = acc + (half ? bv : bk)[r * 256 + h * D_ + d];
    }
    __syncthreads();

    const int c = tid;                 // 0..255
    if (half == 0) {
        float wl = 0.f;
        const float* wqp = Wq + (size_t)rh * D_ * C_ + c;
        #pragma unroll
        for (int d = 0; d < D_; ++d)
            wl = fmaf(kv[d], wqp[(size_t)d * C_], wl);
        WLt[c * RH_ + rh] = wl;        // [c][rh]

        if (tid < D_) {
            float s = kv[tid] * bq[rh * D_ + tid];
            s += __shfl_xor(s, 1);  s += __shfl_xor(s, 2);  s += __shfl_xor(s, 4);
            s += __shfl_xor(s, 8);  s += __shfl_xor(s, 16);
            if (tid == 0) c0o[rh] = s;
        }
    } else {
        float uu = 0.f;
        const float* wmp = Wm + (size_t)c * KD_ + rh * D_;
        #pragma unroll
        for (int d4 = 0; d4 < D_; d4 += 4) {
            const float4 m4 = LD4(wmp + d4);
            uu = fmaf(kv[d4 + 0], m4.x, uu);
            uu = fmaf(kv[d4 + 1], m4.y, uu);
            uu = fmaf(kv[d4 + 2], m4.z, uu);
            uu = fmaf(kv[d4 + 3], m4.w, uu);
        }
        Uo[rh * C_ + c] = uu;          // [rh][c]
    }
}

// ---------------------------------------------------------------------------
// GEMM1: L[rh][p] = sum_c WLt[c][rh] * z[b][c][xy]   (no bias; c0 added later)
// grid (256 p-tiles, 2 m-halves) x 512 thr. Wave owns 8 rh rows; lane = p.
// z: per-lane VMEM b32 chunks (vmcnt pipelined). Weights: wave-uniform s_load.
// NO LDS. VGPR ~45 -> 8 waves/SIMD.
// ---------------------------------------------------------------------------
__global__ __launch_bounds__(512, 8)
void gemm1(const float* __restrict__ z,
           const float* __restrict__ WLt,
           float* __restrict__ L)
{
    const int tid   = threadIdx.x;
    const int lane  = tid & 63;
    const int w     = __builtin_amdgcn_readfirstlane(tid >> 6);  // 0..7
    const int ptile = blockIdx.x;      // 0..255
    const int mh    = blockIdx.y;      // 0..1
    const int b     = ptile >> 4;
    const int xy0   = (ptile & 15) * 64;
    const int rh0   = mh * 64 + w * 8;

    const float* zb = z + ((size_t)b * C_) * XY_ + xy0 + lane;
    const float* wp = WLt + rh0;       // wave-uniform base; [c][rh]

    float acc[8];
    #pragma unroll
    for (int m = 0; m < 8; ++m) acc[m] = 0.f;

    #pragma unroll 2
    for (int cc = 0; cc < C_; cc += 16) {
        float zq[16];
        #pragma unroll
        for (int j = 0; j < 16; ++j)
            zq[j] = zb[(size_t)(cc + j) * XY_];
        #pragma unroll
        for (int j = 0; j < 16; ++j) {
            const float* wr = wp + (size_t)(cc + j) * RH_;
            #pragma unroll
            for (int m = 0; m < 8; ++m)
                acc[m] = fmaf(wr[m], zq[j], acc[m]);
        }
    }

    float* Lb = L + (size_t)rh0 * NPOS + ptile * 64 + lane;
    #pragma unroll
    for (int m = 0; m < 8; ++m)
        Lb[(size_t)m * NPOS] = acc[m];
}

// ---------------------------------------------------------------------------
// Fused softmax + GEMM2: out[b][c][xy] = sum_rh U[rh][c]*attn[rh][p] + bm[c]
// grid (256 p-tiles, 2 c-halves) x 512 thr. Wave owns 16 c rows; lane = p.
// Per h (8 iterations): read the 16 r-logits for (h, p) from L (coalesced
// VMEM), softmax IN REGISTERS (attn never touches memory), then accumulate
// those 16 rh-steps into acc[16] with wave-uniform s_load weights.
// ZERO DS instructions -> lgkm counter carries SMEM only. VGPR ~50.
// ---------------------------------------------------------------------------
__global__ __launch_bounds__(512, 8)
void gemm2_sm(const float* __restrict__ L,
              const float* __restrict__ Uo,
              const float* __restrict__ c0v,
              const float* __restrict__ bm,
              float* __restrict__ out)
{
    const int tid   = threadIdx.x;
    const int lane  = tid & 63;
    const int w     = __builtin_amdgcn_readfirstlane(tid >> 6);  // 0..7
    const int ptile = blockIdx.x;      // 0..255
    const int ch    = blockIdx.y;      // 0..1
    const int b     = ptile >> 4;
    const int xy0   = (ptile & 15) * 64;
    const int cbase = ch * 128 + w * 16;

    const float* Lb = L + ptile * 64 + lane;

    float acc[16];
    #pragma unroll
    for (int j = 0; j < 16; ++j) acc[j] = 0.f;

    #pragma unroll 1
    for (int h = 0; h < NH_; ++h) {
        // load 16 logits for this (h, p) column + bias
        float v[16];
        #pragma unroll
        for (int r = 0; r < R_; ++r)
            v[r] = Lb[(size_t)(r * NH_ + h) * NPOS] + c0v[r * NH_ + h];

        // softmax over r, in registers
        float mx = v[0];
        #pragma unroll
        for (int r = 1; r < R_; ++r) mx = fmaxf(mx, v[r]);
        float s = 0.f;
        #pragma unroll
        for (int r = 0; r < R_; ++r) { v[r] = __expf(v[r] - mx); s += v[r]; }
        const float inv = 1.f / s;

        // accumulate the 16 rh rows of this head into acc
        #pragma unroll
        for (int r = 0; r < R_; ++r) {
            const float av = v[r] * inv;
            const float* ur = Uo + (size_t)(r * NH_ + h) * C_ + cbase;  // uniform
            #pragma unroll
            for (int j = 0; j < 16; ++j)
                acc[j] = fmaf(ur[j], av, acc[j]);
        }
    }

    float* ob = out + ((size_t)b * C_ + cbase) * XY_ + xy0 + lane;
    #pragma unroll
    for (int j = 0; j < 16; ++j)
        ob[(size_t)j * XY_] = acc[j] + bm[cbase + j];
}

// ---------------------------------------------------------------------------
extern "C" void kernel_launch(void* const* d_in, const int* in_sizes, int n_in,
                              void* d_out, int out_size, void* d_ws, size_t ws_size,
                              hipStream_t stream)
{
    const float* z    = (const float*)d_in[0];
    const float* rims = (const float*)d_in[1];
    const float* Wk   = (const float*)d_in[2];
    const float* bk   = (const float*)d_in[3];
    const float* Wv   = (const float*)d_in[4];
    const float* bv   = (const float*)d_in[5];
    const float* Wq   = (const float*)d_in[6];
    const float* bq   = (const float*)d_in[7];
    const float* Wm   = (const float*)d_in[8];
    const float* bm   = (const float*)d_in[9];
    float* out = (float*)d_out;

    // ws layout: WLt (C_*RH_) | Uo (RH_*C_) | c0 (RH_) | pad | L (RH_*NPOS)
    float* WLt = (float*)d_ws;
    float* Uo  = WLt + C_ * RH_;
    float* c0o = Uo + RH_ * C_;
    float* L   = c0o + 256;            // 256-float pad keeps L 1KB-aligned

    rims_precompute<<<2 * RH_, 256, 0, stream>>>(rims, Wk, bk, Wv, bv, Wq, bq, Wm,
                                                 WLt, Uo, c0o);
    gemm1<<<dim3(256, 2), 512, 0, stream>>>(z, WLt, L);
    gemm2_sm<<<dim3(256, 2), 512, 0, stream>>>(L, Uo, c0o, bm, out);
}

// Round 10
// 59.203 us; speedup vs baseline: 1.1602x; 1.1602x over previous
//
#include <hip/hip_runtime.h>
#include <cstdint>
#include <cstddef>

// Dims (fixed by the reference)
#define R_   16
#define NH_  8
#define D_   32
#define C_   256
#define B_   16
#define XY_  1024      // 32*32
#define RH_  128       // R_*NH_
#define KD_  4096      // R_*NH_*D_
#define NPOS (B_*XY_)  // 16384 positions

#define LD4(p) (*reinterpret_cast<const float4*>(p))

// ---------------------------------------------------------------------------
// Precompute, 2x parallel (256 blocks): bid = rh*2 + half.
//   half 0: k[d] = Wk[r,h*D+d,:]·rims[r,:]+bk  ->  WLt[c][rh], c0[rh]
//   half 1: v[d] = Wv[...]·rims+bv             ->  Uo[rh][c]
// ~HBM-bound on 42 MB of weights (~7 us floor).
// ---------------------------------------------------------------------------
__global__ __launch_bounds__(256)
void rims_precompute(const float* __restrict__ rims,
                     const float* __restrict__ Wk,
                     const float* __restrict__ bk,
                     const float* __restrict__ Wv,
                     const float* __restrict__ bv,
                     const float* __restrict__ Wq,
                     const float* __restrict__ bq,
                     const float* __restrict__ Wm,
                     float* __restrict__ WLt,
                     float* __restrict__ Uo,
                     float* __restrict__ c0o)
{
    const int bid  = blockIdx.x;       // 0..255
    const int rh   = bid >> 1;         // 0..127
    const int half = bid & 1;          // 0: k/WLt, 1: v/Uo
    const int r    = rh >> 3;
    const int h    = rh & 7;
    const int tid  = threadIdx.x;

    __shared__ float kv[D_];

    {
        const int d    = tid >> 3;     // 0..31
        const int part = tid & 7;      // 0..7
        const float* Wsrc = (half ? Wv : Wk)
                          + ((size_t)r * 256 + h * D_ + d) * C_ + part * 32;
        const float* rr   = rims + r * C_ + part * 32;
        float a0 = 0.f, a1 = 0.f, a2 = 0.f, a3 = 0.f;
        #pragma unroll
        for (int j = 0; j < 8; ++j) {
            const float4 wv4 = LD4(Wsrc + j * 4);
            const float4 xv4 = LD4(rr + j * 4);
            a0 = fmaf(wv4.x, xv4.x, a0); a1 = fmaf(wv4.y, xv4.y, a1);
            a2 = fmaf(wv4.z, xv4.z, a2); a3 = fmaf(wv4.w, xv4.w, a3);
        }
        float acc = (a0 + a1) + (a2 + a3);
        acc += __shfl_xor(acc, 1);
        acc += __shfl_xor(acc, 2);
        acc += __shfl_xor(acc, 4);
        if (part == 0)
            kv[d] = acc + (half ? bv : bk)[r * 256 + h * D_ + d];
    }
    __syncthreads();

    const int c = tid;                 // 0..255
    if (half == 0) {
        float wl = 0.f;
        const float* wqp = Wq + (size_t)rh * D_ * C_ + c;
        #pragma unroll
        for (int d = 0; d < D_; ++d)
            wl = fmaf(kv[d], wqp[(size_t)d * C_], wl);
        WLt[c * RH_ + rh] = wl;        // [c][rh]

        if (tid < D_) {
            float s = kv[tid] * bq[rh * D_ + tid];
            s += __shfl_xor(s, 1);  s += __shfl_xor(s, 2);  s += __shfl_xor(s, 4);
            s += __shfl_xor(s, 8);  s += __shfl_xor(s, 16);
            if (tid == 0) c0o[rh] = s;
        }
    } else {
        float uu = 0.f;
        const float* wmp = Wm + (size_t)c * KD_ + rh * D_;
        #pragma unroll
        for (int d4 = 0; d4 < D_; d4 += 4) {
            const float4 m4 = LD4(wmp + d4);
            uu = fmaf(kv[d4 + 0], m4.x, uu);
            uu = fmaf(kv[d4 + 1], m4.y, uu);
            uu = fmaf(kv[d4 + 2], m4.z, uu);
            uu = fmaf(kv[d4 + 3], m4.w, uu);
        }
        Uo[rh * C_ + c] = uu;          // [rh][c]
    }
}

// ---------------------------------------------------------------------------
// GEMM1: L[rh][p] = sum_c WLt[c][rh] * z[b][c][xy]
// grid (256 ptiles, 8 rh-groups) = 2048 blocks x 256 thr (4 waves).
// Wave kq handles K-quarter [64kq, 64kq+64) for the block's 16 rh rows.
// 8 blocks/CU -> 8 INDEPENDENT waves/SIMD; lane = p.
// z: per-lane in-order VMEM stream. Weights: uniform s_load, 4-step batches.
// 4-way split-K partials reduced via 16 KB LDS, single barrier.
// ---------------------------------------------------------------------------
__global__ __launch_bounds__(256, 8)
void gemm1(const float* __restrict__ z,
           const float* __restrict__ WLt,
           float* __restrict__ L)
{
    __shared__ float P[4][16][64];     // 16 KB

    const int tid   = threadIdx.x;
    const int lane  = tid & 63;
    const int kq    = __builtin_amdgcn_readfirstlane(tid >> 6);  // 0..3
    const int ptile = blockIdx.x;      // 0..255
    const int rh0   = blockIdx.y * 16; // 0..112
    const int b     = ptile >> 4;
    const int xy0   = (ptile & 15) * 64;

    const float* zb = z + ((size_t)b * C_ + kq * 64) * XY_ + xy0 + lane;
    const float* wp = WLt + (size_t)(kq * 64) * RH_ + rh0;   // uniform

    float acc[16];
    #pragma unroll
    for (int m = 0; m < 16; ++m) acc[m] = 0.f;

    // 64 k-steps in batches of 4: 4 z loads + 4x16 uniform weights + 64 FMA
    #pragma unroll 4
    for (int j4 = 0; j4 < 64; j4 += 4) {
        const float z0 = zb[(size_t)(j4 + 0) * XY_];
        const float z1 = zb[(size_t)(j4 + 1) * XY_];
        const float z2 = zb[(size_t)(j4 + 2) * XY_];
        const float z3 = zb[(size_t)(j4 + 3) * XY_];

        const float* w0 = wp + (size_t)(j4 + 0) * RH_;
        const float* w1 = wp + (size_t)(j4 + 1) * RH_;
        const float* w2 = wp + (size_t)(j4 + 2) * RH_;
        const float* w3 = wp + (size_t)(j4 + 3) * RH_;

        #pragma unroll
        for (int m = 0; m < 16; ++m) acc[m] = fmaf(w0[m], z0, acc[m]);
        #pragma unroll
        for (int m = 0; m < 16; ++m) acc[m] = fmaf(w1[m], z1, acc[m]);
        #pragma unroll
        for (int m = 0; m < 16; ++m) acc[m] = fmaf(w2[m], z2, acc[m]);
        #pragma unroll
        for (int m = 0; m < 16; ++m) acc[m] = fmaf(w3[m], z3, acc[m]);
    }

    #pragma unroll
    for (int m = 0; m < 16; ++m)
        P[kq][m][lane] = acc[m];
    __syncthreads();

    // reduce 4 partials; thread -> (m = (tid>>6) + 4i, p = lane)
    float* Lb = L + (size_t)rh0 * NPOS + ptile * 64 + lane;
    #pragma unroll
    for (int i = 0; i < 4; ++i) {
        const int m = (tid >> 6) + i * 4;
        const float s = (P[0][m][lane] + P[1][m][lane])
                      + (P[2][m][lane] + P[3][m][lane]);
        Lb[(size_t)m * NPOS] = s;
    }
}

// ---------------------------------------------------------------------------
// Fused softmax + GEMM2: out[b][c][xy] = sum_rh U[rh][c]*attn[rh][p] + bm[c]
// grid (256 ptiles, 4) x 256 thr (4 waves); wave w -> c-group blockIdx.y*4+w
// (16 groups x 16 c-rows). Per h: 16 logits from L (coalesced VMEM), softmax
// IN REGISTERS, then 16 rh-steps into acc[16] with uniform s_load weights
// (rows processed in pairs to widen the lgkm batch). No LDS at all.
// ---------------------------------------------------------------------------
__global__ __launch_bounds__(256, 8)
void gemm2_sm(const float* __restrict__ L,
              const float* __restrict__ Uo,
              const float* __restrict__ c0v,
              const float* __restrict__ bm,
              float* __restrict__ out)
{
    const int tid   = threadIdx.x;
    const int lane  = tid & 63;
    const int w     = __builtin_amdgcn_readfirstlane(tid >> 6);  // 0..3
    const int ptile = blockIdx.x;      // 0..255
    const int b     = ptile >> 4;
    const int xy0   = (ptile & 15) * 64;
    const int cbase = (blockIdx.y * 4 + w) * 16;   // 0..240

    const float* Lb = L + ptile * 64 + lane;

    float acc[16];
    #pragma unroll
    for (int j = 0; j < 16; ++j) acc[j] = 0.f;

    #pragma unroll 1
    for (int h = 0; h < NH_; ++h) {
        // 16 logits for (h, p) + c0 bias
        float v[16];
        #pragma unroll
        for (int r = 0; r < R_; ++r)
            v[r] = Lb[(size_t)(r * NH_ + h) * NPOS] + c0v[r * NH_ + h];

        // softmax over r, in registers
        float mx = v[0];
        #pragma unroll
        for (int r = 1; r < R_; ++r) mx = fmaxf(mx, v[r]);
        float s = 0.f;
        #pragma unroll
        for (int r = 0; r < R_; ++r) { v[r] = __expf(v[r] - mx); s += v[r]; }
        const float inv = 1.f / s;

        // accumulate 16 rh rows (pairs -> wider s_load batches)
        #pragma unroll
        for (int r = 0; r < R_; r += 2) {
            const float a0 = v[r] * inv;
            const float a1 = v[r + 1] * inv;
            const float* u0 = Uo + (size_t)((r    ) * NH_ + h) * C_ + cbase;
            const float* u1 = Uo + (size_t)((r + 1) * NH_ + h) * C_ + cbase;
            #pragma unroll
            for (int j = 0; j < 16; ++j) acc[j] = fmaf(u0[j], a0, acc[j]);
            #pragma unroll
            for (int j = 0; j < 16; ++j) acc[j] = fmaf(u1[j], a1, acc[j]);
        }
    }

    float* ob = out + ((size_t)b * C_ + cbase) * XY_ + xy0 + lane;
    #pragma unroll
    for (int j = 0; j < 16; ++j)
        ob[(size_t)j * XY_] = acc[j] + bm[cbase + j];
}

// ---------------------------------------------------------------------------
extern "C" void kernel_launch(void* const* d_in, const int* in_sizes, int n_in,
                              void* d_out, int out_size, void* d_ws, size_t ws_size,
                              hipStream_t stream)
{
    const float* z    = (const float*)d_in[0];
    const float* rims = (const float*)d_in[1];
    const float* Wk   = (const float*)d_in[2];
    const float* bk   = (const float*)d_in[3];
    const float* Wv   = (const float*)d_in[4];
    const float* bv   = (const float*)d_in[5];
    const float* Wq   = (const float*)d_in[6];
    const float* bq   = (const float*)d_in[7];
    const float* Wm   = (const float*)d_in[8];
    const float* bm   = (const float*)d_in[9];
    float* out = (float*)d_out;

    // ws layout: WLt (C_*RH_) | Uo (RH_*C_) | c0 (RH_) | pad | L (RH_*NPOS)
    float* WLt = (float*)d_ws;
    float* Uo  = WLt + C_ * RH_;
    float* c0o = Uo + RH_ * C_;
    float* L   = c0o + 256;            // pad keeps L 1KB-aligned

    rims_precompute<<<2 * RH_, 256, 0, stream>>>(rims, Wk, bk, Wv, bv, Wq, bq, Wm,
                                                 WLt, Uo, c0o);
    gemm1<<<dim3(256, 8), 256, 0, stream>>>(z, WLt, L);
    gemm2_sm<<<dim3(256, 4), 256, 0, stream>>>(L, Uo, c0o, bm, out);
}